// Round 2
// baseline (218.087 us; speedup 1.0000x reference)
//
#include <hip/hip_runtime.h>

// Problem constants
constexpr int S = 7, NB = 2, C = 20, E = 30;      // E = NB*5 + C = 30
constexpr int BATCH = 16384;
constexpr int NCELLS = BATCH * S * S;             // 802816

__global__ void zero_out_kernel(float* out) {
    if (threadIdx.x < 5) out[threadIdx.x] = 0.0f;
}

// No-LDS version: each thread owns one cell (30 contiguous floats = 120 B).
// Lane i's 15 float2 loads stride 120 B across the wave; the first load
// instruction pulls the wave's whole 7680 B span into L1 (every line fully
// consumed), the rest are L1 hits. No LDS staging -> no 62 KB LDS cap
// (was 2 blocks/CU = 8 waves/CU) and no load->ds_write->ds_read serial
// chain. VGPR-bound at ~88 regs -> 16 waves/CU.
__global__ __launch_bounds__(256, 4) void yolo_loss_kernel(
    const float* __restrict__ pred,
    const float* __restrict__ tgt,
    float* __restrict__ out)
{
    const int tid      = blockIdx.x * blockDim.x + threadIdx.x;
    const int nthreads = gridDim.x * blockDim.x;
    const int lane     = threadIdx.x & 63;
    const int wv       = threadIdx.x >> 6;

    float acc0 = 0.f, acc1 = 0.f, acc2 = 0.f, acc3 = 0.f, acc4 = 0.f;

    for (int cell = tid; cell < NCELLS; cell += nthreads) {
        const float2* gp = reinterpret_cast<const float2*>(pred) + (size_t)cell * 15;
        const float2* gt = reinterpret_cast<const float2*>(tgt)  + (size_t)cell * 15;

        // Issue all 30 independent loads before any use; compiler batches
        // them and inserts a single vmcnt wait before consumption.
        float p[30], t[30];
        #pragma unroll
        for (int j = 0; j < 15; ++j) {
            float2 a = gp[j]; p[2*j] = a.x; p[2*j+1] = a.y;
        }
        #pragma unroll
        for (int j = 0; j < 15; ++j) {
            float2 b = gt[j]; t[2*j] = b.x; t[2*j+1] = b.y;
        }

        const float tconf = t[4];                 // exactly 0.0 or 1.0
        const float m  = (tconf > 0.0f)  ? 1.0f : 0.0f;
        const float nm = 1.0f - m;

        // IoU of each pred box vs target box 0 (channels 0..3)
        const float t0x1 = t[0], t0y1 = t[1], t0x2 = t[2], t0y2 = t[3];
        const float a2 = (t0x2 - t0x1) * (t0y2 - t0y1);

        float iou[2];
        #pragma unroll
        for (int b = 0; b < 2; ++b) {
            const float px1 = p[5*b+0], py1 = p[5*b+1];
            const float px2 = p[5*b+2], py2 = p[5*b+3];
            const float ltx = fmaxf(px1, t0x1), lty = fmaxf(py1, t0y1);
            const float rbx = fminf(px2, t0x2), rby = fminf(py2, t0y2);
            const float wx = fmaxf(rbx - ltx, 0.0f), wy = fmaxf(rby - lty, 0.0f);
            const float inter = wx * wy;
            const float a1 = (px2 - px1) * (py2 - py1);
            iou[b] = inter / (a1 + a2 - inter);
        }

        const float max_iou = fmaxf(iou[0], iou[1]);
        const int r = (iou[0] >= iou[1]) ? 0 : 5;   // first index wins ties

        {   // xy
            const float dx = p[r+0] - t[r+0];
            const float dy = p[r+1] - t[r+1];
            acc0 += m * (dx*dx + dy*dy);
        }
        {   // wh (sqrt space; inputs in (0.05, 0.95) so sqrt args > 0)
            const float dw = sqrtf(p[r+2]) - sqrtf(t[r+2]);
            const float dh = sqrtf(p[r+3]) - sqrtf(t[r+3]);
            acc1 += m * (dw*dw + dh*dh);
        }
        {   // obj
            const float d = p[r+4] - max_iou;
            acc2 += m * d * d;
        }
        {   // noobj (channels 4, 9)
            const float d0 = p[4] - t[4];
            const float d1 = p[9] - t[9];
            acc3 += nm * (d0*d0 + d1*d1);
        }
        {   // class (channels 10..29)
            float cl = 0.f;
            #pragma unroll
            for (int k = 10; k < 30; ++k) {
                const float d = p[k] - t[k];
                cl += d * d;
            }
            acc4 += m * cl;
        }
    }

    // ---- reduction: wave (64) -> block -> global atomics ----
    float acc[5] = {acc0, acc1, acc2, acc3, acc4};
    __shared__ float wave_sums[4][5];
    #pragma unroll
    for (int i = 0; i < 5; ++i) {
        float v = acc[i];
        #pragma unroll
        for (int o = 32; o > 0; o >>= 1)
            v += __shfl_down(v, o, 64);
        if (lane == 0) wave_sums[wv][i] = v;
    }
    __syncthreads();

    if (threadIdx.x < 5) {
        const float v = wave_sums[0][threadIdx.x] + wave_sums[1][threadIdx.x]
                      + wave_sums[2][threadIdx.x] + wave_sums[3][threadIdx.x];
        atomicAdd(out + threadIdx.x, v);
    }
}

extern "C" void kernel_launch(void* const* d_in, const int* in_sizes, int n_in,
                              void* d_out, int out_size, void* d_ws, size_t ws_size,
                              hipStream_t stream) {
    const float* pred = (const float*)d_in[0];
    const float* tgt  = (const float*)d_in[1];
    float* out = (float*)d_out;

    hipLaunchKernelGGL(zero_out_kernel, dim3(1), dim3(64), 0, stream, out);

    // 1024 blocks x 256 threads = 4096 waves; fully resident at 16 waves/CU
    // (VGPR-bound, ~88 regs). Each thread handles 3-4 cells via grid-stride.
    hipLaunchKernelGGL(yolo_loss_kernel, dim3(1024), dim3(256), 0, stream,
                       pred, tgt, out);
}